// Round 2
// baseline (336.857 us; speedup 1.0000x reference)
//
#include <hip/hip_runtime.h>
#include <hip/hip_bf16.h>

// PatchMask: out[b,c,h,w] = x[b,c,h,w] * keep_mask[b, h/16, w/16]
// x: fp32 [64,3,512,512] (201 MB), keep_mask: bool->int32 [64,32,32]
//
// R2: one thread = 16 consecutive pixels (4x float4), aligned to the 16-wide
// patch grid => mask decision is uniform per thread. Masked threads skip all
// 4 global loads (exec-masked off) and store zeros: read traffic drops by the
// mask ratio (~35%), total HBM traffic 402 -> ~332 MB.
//
// 50,331,648 elems / 16 per thread = 3,145,728 threads = 12,288 blocks x 256.

#define W_DIM 512
#define H_DIM 512
#define CH 3

__global__ __launch_bounds__(256) void PatchMask_kernel(
    const float4* __restrict__ x,
    const int* __restrict__ mask,
    float4* __restrict__ out)
{
    int t  = blockIdx.x * blockDim.x + threadIdx.x;
    int i4 = t << 2;                 // base float4 index (4 per thread)
    int e  = t << 4;                 // base element index (16 per thread)

    int w  = e & (W_DIM - 1);        // multiple of 16 -> single patch column
    int h  = (e >> 9) & (H_DIM - 1);
    int b  = (e >> 18) / CH;         // magic-mul division by 3

    // mask is [B, 32, 32]
    int mi = (b << 10) + ((h >> 4) << 5) + (w >> 4);

    if (mask[mi] != 0) {
        float4 v0 = x[i4 + 0];
        float4 v1 = x[i4 + 1];
        float4 v2 = x[i4 + 2];
        float4 v3 = x[i4 + 3];
        out[i4 + 0] = v0;
        out[i4 + 1] = v1;
        out[i4 + 2] = v2;
        out[i4 + 3] = v3;
    } else {
        float4 z = make_float4(0.f, 0.f, 0.f, 0.f);
        out[i4 + 0] = z;
        out[i4 + 1] = z;
        out[i4 + 2] = z;
        out[i4 + 3] = z;
    }
}

extern "C" void kernel_launch(void* const* d_in, const int* in_sizes, int n_in,
                              void* d_out, int out_size, void* d_ws, size_t ws_size,
                              hipStream_t stream) {
    const float4* x = (const float4*)d_in[0];
    const int* mask = (const int*)d_in[1];
    float4* out     = (float4*)d_out;

    int n_threads = out_size >> 4;               // 3,145,728
    int block = 256;
    int grid = (n_threads + block - 1) / block;  // 12,288

    PatchMask_kernel<<<grid, block, 0, stream>>>(x, mask, out);
}

// Round 3
// 329.373 us; speedup vs baseline: 1.0227x; 1.0227x over previous
//
#include <hip/hip_runtime.h>
#include <hip/hip_bf16.h>

// PatchMask: out[b,c,h,w] = x[b,c,h,w] * keep_mask[b, h/16, w/16]
// x: fp32 [64,3,512,512] (201 MB), keep_mask: bool->int32 [64,32,32]
//
// R3: dense lane-contiguous float4 addressing (lane i -> base + 16i B) with a
// per-lane PREDICATED load: each aligned 4-lane group (64 B) covers exactly 16
// consecutive pixels = one patch-row segment, so exec-masked loads skip whole
// cache lines for masked patches. Reads: 201 -> ~131 MB; writes 201 MB (d_out
// is re-poisoned, must be fully written). 4 float4s per thread strided by
// quarter-array for ILP, each instruction stays lane-dense.

#define W_DIM 512
#define H_DIM 512
#define CH 3

__global__ __launch_bounds__(256) void PatchMask_kernel(
    const float4* __restrict__ x,
    const int* __restrict__ mask,
    float4* __restrict__ out,
    int q)                            // quarter of total float4 count
{
    int t = blockIdx.x * blockDim.x + threadIdx.x;

#pragma unroll
    for (int k = 0; k < 4; ++k) {
        int i = t + k * q;            // float4 index; lanes consecutive
        int e = i << 2;               // element index
        int w = e & (W_DIM - 1);
        int h = (e >> 9) & (H_DIM - 1);
        int b = (e >> 18) / CH;       // magic-mul
        int mi = (b << 10) + ((h >> 4) << 5) + (w >> 4);

        float4 v = make_float4(0.f, 0.f, 0.f, 0.f);
        if (mask[mi] != 0) {
            v = x[i];                 // exec-masked: skipped lines not fetched
        }
        out[i] = v;
    }
}

extern "C" void kernel_launch(void* const* d_in, const int* in_sizes, int n_in,
                              void* d_out, int out_size, void* d_ws, size_t ws_size,
                              hipStream_t stream) {
    const float4* x = (const float4*)d_in[0];
    const int* mask = (const int*)d_in[1];
    float4* out     = (float4*)d_out;

    int n4 = out_size >> 2;          // 12,582,912 float4s
    int q  = n4 >> 2;                // 3,145,728 per quarter
    int block = 256;
    int grid = q / block;            // 12,288 blocks

    PatchMask_kernel<<<grid, block, 0, stream>>>(x, mask, out, q);
}